// Round 1
// baseline (2194.319 us; speedup 1.0000x reference)
//
#include <hip/hip_runtime.h>
#include <hip/hip_bf16.h>

// ---------------------------------------------------------------------------
// myLSTM: LSTM(B=64,T=512,D=256,H=256) + single-head attn (only t=0 query is
// consumed by the head!) + MLP head.
// Pipeline:
//   prep_x      : x fp32 -> bf16 (same layout)
//   prep_wit    : Wi fp32 [256,1024] -> bf16 transposed [1024,256]
//   zero_flags  : clear inter-WG sync flags (ws is poisoned 0xAA every call)
//   xg_gemm     : xg = x@Wi + b   (bf16 MFMA, 128x128 tiles, bf16 output)
//   lstm_scan   : persistent 64-WG kernel, 512 steps, h exchanged via
//                 agent-scope flags (4 batch-groups x 16 gate-groups)
//   attn_qu     : q0 = h0@Wq+bq ; u = Wk@(scale*q0) ; cb = scale*q0.bk
//   attn_sm     : scores = u.h[b,t]+cb -> softmax -> hbar = sum attn*h
//   head        : o0=hbar@Wv+bv ; o1=o0@Wo+bo ; z=relu(o1@W1+b1) ; out=z@W2+b2
// ---------------------------------------------------------------------------

typedef __attribute__((ext_vector_type(8))) short short8;   // 8 x bf16 (4 VGPR)
typedef __attribute__((ext_vector_type(4))) float float4v;  // MFMA acc

__device__ __forceinline__ unsigned short f2bf(float f) {  // RNE f32->bf16
  unsigned u = __builtin_bit_cast(unsigned, f);
  return (unsigned short)((u + 0x7fffu + ((u >> 16) & 1u)) >> 16);
}
__device__ __forceinline__ float bf2f(unsigned short h) {
  return __builtin_bit_cast(float, ((unsigned)h) << 16);
}
__device__ __forceinline__ float bcl(unsigned u) {  // low bf16 of dword
  return __builtin_bit_cast(float, u << 16);
}
__device__ __forceinline__ float bch(unsigned u) {  // high bf16 of dword
  return __builtin_bit_cast(float, u & 0xffff0000u);
}
__device__ __forceinline__ float sigm(float x) { return 1.f / (1.f + __expf(-x)); }
__device__ __forceinline__ float tanh_f(float x) { return 1.f - 2.f / (1.f + __expf(2.f * x)); }

// ---------------------------------------------------------------- prep kernels
__global__ void prep_x(const float* __restrict__ x, unsigned short* __restrict__ xbf) {
  size_t i = ((size_t)blockIdx.x * 256 + threadIdx.x) * 4;  // 8,388,608 elems
  float4 v = *(const float4*)&x[i];
  unsigned long long pk = (unsigned long long)f2bf(v.x)
                        | ((unsigned long long)f2bf(v.y) << 16)
                        | ((unsigned long long)f2bf(v.z) << 32)
                        | ((unsigned long long)f2bf(v.w) << 48);
  *(unsigned long long*)&xbf[i] = pk;
}

__global__ void prep_wit(const float* __restrict__ Wi, unsigned short* __restrict__ WiT) {
  size_t i = ((size_t)blockIdx.x * 256 + threadIdx.x) * 4;  // 262,144 elems
  float4 v = *(const float4*)&Wi[i];
  int k = (int)(i >> 10), n = (int)(i & 1023);
  WiT[(size_t)(n + 0) * 256 + k] = f2bf(v.x);
  WiT[(size_t)(n + 1) * 256 + k] = f2bf(v.y);
  WiT[(size_t)(n + 2) * 256 + k] = f2bf(v.z);
  WiT[(size_t)(n + 3) * 256 + k] = f2bf(v.w);
}

__global__ void zero_flags(unsigned* __restrict__ f) {
  f[(size_t)blockIdx.x * 256 + threadIdx.x] = 0u;  // 32768 dwords
}

// ---------------------------------------------------------------- xg = x@Wi+b
#define XKP 40  // LDS k-pitch (shorts): 80B rows -> 16B-aligned b128, ~2-way banks
__global__ __launch_bounds__(256) void xg_gemm(const unsigned short* __restrict__ xbf,
                                               const unsigned short* __restrict__ WiT,
                                               const float* __restrict__ bias,
                                               unsigned short* __restrict__ xg) {
  __shared__ unsigned short As[128 * XKP];
  __shared__ unsigned short Bs[128 * XKP];
  const int tid = threadIdx.x;
  const int n0 = blockIdx.x * 128, m0 = blockIdx.y * 128;
  const int wave = tid >> 6, lane = tid & 63, quad = lane >> 4, l16 = lane & 15;
  const int wm = wave >> 1, wn = wave & 1;

  float4v acc[4][4];
#pragma unroll
  for (int i = 0; i < 4; ++i)
#pragma unroll
    for (int j = 0; j < 4; ++j) acc[i][j] = (float4v){0.f, 0.f, 0.f, 0.f};

  const int rr = tid >> 2, c8 = (tid & 3) * 8;  // staging coords (16B per thread)
  for (int k0 = 0; k0 < 256; k0 += 32) {
#pragma unroll
    for (int pp = 0; pp < 2; ++pp) {
      int r = pp * 64 + rr;
      *(uint4*)&As[r * XKP + c8] = *(const uint4*)&xbf[(size_t)(m0 + r) * 256 + k0 + c8];
      *(uint4*)&Bs[r * XKP + c8] = *(const uint4*)&WiT[(size_t)(n0 + r) * 256 + k0 + c8];
    }
    __syncthreads();
#pragma unroll
    for (int mt = 0; mt < 4; ++mt) {
      short8 af = *(const short8*)&As[(wm * 64 + mt * 16 + l16) * XKP + quad * 8];
#pragma unroll
      for (int nt = 0; nt < 4; ++nt) {
        short8 bf = *(const short8*)&Bs[(wn * 64 + nt * 16 + l16) * XKP + quad * 8];
        acc[mt][nt] = __builtin_amdgcn_mfma_f32_16x16x32_bf16(af, bf, acc[mt][nt], 0, 0, 0);
      }
    }
    __syncthreads();
  }
  // epilogue: +bias, bf16 store.  C layout: col=lane&15, row=quad*4+reg.
#pragma unroll
  for (int nt = 0; nt < 4; ++nt) {
    int col = n0 + wn * 64 + nt * 16 + l16;
    float bv = bias[col];
#pragma unroll
    for (int mt = 0; mt < 4; ++mt) {
#pragma unroll
      for (int r = 0; r < 4; ++r) {
        int row = m0 + wm * 64 + mt * 16 + quad * 4 + r;
        xg[(size_t)row * 1024 + col] = f2bf(acc[mt][nt][r] + bv);
      }
    }
  }
}

// ---------------------------------------------------------------- LSTM scan
// 64 WGs: bg = wg>>4 (4 batch groups of 16), gg = wg&15 (16 units each).
// Wave w handles gate type w (cols w*16..w*16+15 of the local 64-col slice).
#define KP2 264  // 528B rows: 16B aligned, 2-way banks on frag reads
__global__ __launch_bounds__(256) void lstm_scan(const float* __restrict__ Wh,
                                                 const unsigned short* __restrict__ xgbuf,
                                                 unsigned short* __restrict__ hout,
                                                 unsigned short* __restrict__ hx,
                                                 unsigned* __restrict__ flags) {
  __shared__ unsigned short WhS[64 * KP2];  // [local col][k] bf16
  __shared__ unsigned short hA[16 * KP2];   // [batch][k]  h_{t-1} bf16
  __shared__ float preS[16 * 68];           // [batch][local col] fp32
  __shared__ float cS[256];                 // [batch][unit] fp32 cell state
  const int tid = threadIdx.x;
  const int wg = blockIdx.x, bg = wg >> 4, gg = wg & 15;
  const int wave = tid >> 6, lane = tid & 63, quad = lane >> 4, l16 = lane & 15;

  // stage Wh slice: WhS[gt*16+uu][k] = Wh[k][gt*256 + gg*16 + uu]   (bf16)
  {
    int uu = tid & 15, kh = tid >> 4;  // 16x16 threads
#pragma unroll
    for (int gt = 0; gt < 4; ++gt)
      for (int kb = 0; kb < 16; ++kb) {
        int k = kb * 16 + kh;
        WhS[(gt * 16 + uu) * KP2 + k] = f2bf(Wh[(size_t)k * 1024 + gt * 256 + gg * 16 + uu]);
      }
  }
  for (int i = tid; i < 16 * KP2; i += 256) hA[i] = 0;  // h_{-1} = 0
  cS[tid] = 0.f;                                        // c_{-1} = 0
  __syncthreads();

  const int b_loc = tid >> 4, u_loc = tid & 15;
  const size_t xg_base = ((size_t)(bg * 16 + b_loc) * 512) * 1024 + gg * 16 + u_loc;
  const size_t ho_base = ((size_t)(bg * 16 + b_loc) * 512) * 256 + gg * 16 + u_loc;
  const int nrow = wave * 16 + l16;

  for (int t = 0; t < 512; ++t) {
    // ---- MFMA: pre[b][c] = h_{t-1} @ WhSlice
    float4v acc = (float4v){0.f, 0.f, 0.f, 0.f};
#pragma unroll
    for (int kt = 0; kt < 8; ++kt) {
      short8 af = *(const short8*)&hA[l16 * KP2 + kt * 32 + quad * 8];
      short8 bf = *(const short8*)&WhS[nrow * KP2 + kt * 32 + quad * 8];
      acc = __builtin_amdgcn_mfma_f32_16x16x32_bf16(af, bf, acc, 0, 0, 0);
    }
#pragma unroll
    for (int r = 0; r < 4; ++r)
      preS[(quad * 4 + r) * 68 + wave * 16 + l16] = acc[r];
    __syncthreads();

    // ---- gates (fp32), write h_t (own 16 units x 16 batches)
    {
      const unsigned short* xgp = xgbuf + xg_base + (size_t)t * 1024;
      float gi = preS[b_loc * 68 + 0 * 16 + u_loc] + bf2f(xgp[0 * 256]);
      float gf = preS[b_loc * 68 + 1 * 16 + u_loc] + bf2f(xgp[1 * 256]);
      float gG = preS[b_loc * 68 + 2 * 16 + u_loc] + bf2f(xgp[2 * 256]);
      float go = preS[b_loc * 68 + 3 * 16 + u_loc] + bf2f(xgp[3 * 256]);
      float c = sigm(gf) * cS[tid] + sigm(gi) * tanh_f(gG);
      cS[tid] = c;
      float h = sigm(go) * tanh_f(c);
      unsigned short hb = f2bf(h);
      hout[ho_base + (size_t)t * 256] = hb;
      int p = t & 1;
      hx[((p * 4 + bg) * 16 + b_loc) * 256 + gg * 16 + u_loc] = hb;
    }
    __syncthreads();  // drains each thread's stores (vmcnt) before flag

    // ---- release own flag; wait for the 16 gate-group flags of this bg
    if (tid == 0)
      __hip_atomic_store(&flags[(bg * 512 + t) * 16 + gg], 1u,
                         __ATOMIC_RELEASE, __HIP_MEMORY_SCOPE_AGENT);
    if (tid < 16) {
      int guard = 0;
      while (__hip_atomic_load(&flags[(bg * 512 + t) * 16 + tid],
                               __ATOMIC_ACQUIRE, __HIP_MEMORY_SCOPE_AGENT) == 0 &&
             guard < 65536)
        ++guard;
    }
    __syncthreads();

    // ---- gather full h_t [16][256] into hA
    {
      int p = t & 1;
      const unsigned long long* src =
          (const unsigned long long*)&hx[(p * 4 + bg) * 16 * 256];
      int b2 = tid >> 4, u0 = (tid & 15) * 16;
#pragma unroll
      for (int i = 0; i < 4; ++i) {
        unsigned long long v = src[(b2 * 256 + u0) / 4 + i];
        *(unsigned long long*)&hA[b2 * KP2 + u0 + i * 4] = v;
      }
    }
    __syncthreads();
  }
}

// ---------------------------------------------------------------- attention
__global__ __launch_bounds__(256) void attn_qu(const unsigned short* __restrict__ hout,
                                               const float* __restrict__ Wq,
                                               const float* __restrict__ bq,
                                               const float* __restrict__ Wk,
                                               const float* __restrict__ bk,
                                               float* __restrict__ us,
                                               float* __restrict__ cbuf) {
  __shared__ float h0S[256], q0S[256], red[256];
  const int b = blockIdx.x, tid = threadIdx.x;
  h0S[tid] = bf2f(hout[(size_t)b * 512 * 256 + tid]);
  __syncthreads();
  float a = 0.f;
  for (int k = 0; k < 256; ++k) a += h0S[k] * Wq[(size_t)k * 256 + tid];
  q0S[tid] = a + bq[tid];
  __syncthreads();
  red[tid] = q0S[tid] * bk[tid];
  __syncthreads();
  for (int s = 128; s > 0; s >>= 1) {
    if (tid < s) red[tid] += red[tid + s];
    __syncthreads();
  }
  if (tid == 0) cbuf[b] = 0.0625f * red[0];
  // u[d] = scale * dot(Wk row d, q0)
  float acc = 0.f;
  const float* wr = &Wk[(size_t)tid * 256];
  for (int e = 0; e < 256; e += 4) {
    float4 w = *(const float4*)&wr[e];
    acc += w.x * q0S[e] + w.y * q0S[e + 1] + w.z * q0S[e + 2] + w.w * q0S[e + 3];
  }
  us[b * 256 + tid] = 0.0625f * acc;
}

__global__ __launch_bounds__(256) void attn_sm(const unsigned short* __restrict__ hout,
                                               const float* __restrict__ us,
                                               const float* __restrict__ cbuf,
                                               float* __restrict__ hbar) {
  __shared__ float sS[512], red[256], hb4[4][256];
  const int b = blockIdx.x, tid = threadIdx.x, wave = tid >> 6, lane = tid & 63;
  const size_t hb_base = (size_t)b * 512 * 256;
  const float u0 = us[b * 256 + lane * 4 + 0], u1 = us[b * 256 + lane * 4 + 1];
  const float u2 = us[b * 256 + lane * 4 + 2], u3 = us[b * 256 + lane * 4 + 3];
  const float cbv = cbuf[b];
  for (int i = 0; i < 128; ++i) {
    int t = i * 4 + wave;
    unsigned long long hv = *(const unsigned long long*)&hout[hb_base + (size_t)t * 256 + lane * 4];
    unsigned lo = (unsigned)hv, hi = (unsigned)(hv >> 32);
    float p = u0 * bcl(lo) + u1 * bch(lo) + u2 * bcl(hi) + u3 * bch(hi);
    for (int m = 1; m < 64; m <<= 1) p += __shfl_xor(p, m, 64);
    if (lane == 0) sS[t] = p + cbv;
  }
  __syncthreads();
  red[tid] = fmaxf(sS[tid], sS[tid + 256]);
  __syncthreads();
  for (int s = 128; s > 0; s >>= 1) {
    if (tid < s) red[tid] = fmaxf(red[tid], red[tid + s]);
    __syncthreads();
  }
  float mx = red[0];
  __syncthreads();
  float e0 = __expf(sS[tid] - mx), e1 = __expf(sS[tid + 256] - mx);
  sS[tid] = e0; sS[tid + 256] = e1;
  red[tid] = e0 + e1;
  __syncthreads();
  for (int s = 128; s > 0; s >>= 1) {
    if (tid < s) red[tid] += red[tid + s];
    __syncthreads();
  }
  float inv = 1.f / red[0];
  // hbar[d] = (sum_t e[t]*h[t,d]) * inv  — per-wave partials over t
  float a0 = 0.f, a1 = 0.f, a2 = 0.f, a3 = 0.f;
  const int d0 = lane * 4;
  for (int i = 0; i < 128; ++i) {
    int t = wave * 128 + i;
    float w = sS[t];
    unsigned long long hv = *(const unsigned long long*)&hout[hb_base + (size_t)t * 256 + d0];
    unsigned lo = (unsigned)hv, hi = (unsigned)(hv >> 32);
    a0 += w * bcl(lo); a1 += w * bch(lo); a2 += w * bcl(hi); a3 += w * bch(hi);
  }
  hb4[wave][d0] = a0; hb4[wave][d0 + 1] = a1; hb4[wave][d0 + 2] = a2; hb4[wave][d0 + 3] = a3;
  __syncthreads();
  hbar[b * 256 + tid] = (hb4[0][tid] + hb4[1][tid] + hb4[2][tid] + hb4[3][tid]) * inv;
}

// ---------------------------------------------------------------- MLP head
__global__ __launch_bounds__(256) void head_k(const float* __restrict__ hbar,
                                              const float* __restrict__ Wv, const float* __restrict__ bv,
                                              const float* __restrict__ Wo, const float* __restrict__ bo,
                                              const float* __restrict__ W1, const float* __restrict__ b1,
                                              const float* __restrict__ W2, const float* __restrict__ b2,
                                              float* __restrict__ out) {
  __shared__ float hS[256], oS[256], o1S[256], zS[32];
  const int b = blockIdx.x, tid = threadIdx.x;
  hS[tid] = hbar[b * 256 + tid];
  __syncthreads();
  float a = 0.f;
  for (int k = 0; k < 256; ++k) a += hS[k] * Wv[(size_t)k * 256 + tid];
  oS[tid] = a + bv[tid];
  __syncthreads();
  a = 0.f;
  for (int k = 0; k < 256; ++k) a += oS[k] * Wo[(size_t)k * 256 + tid];
  o1S[tid] = a + bo[tid];
  __syncthreads();
  if (tid < 32) {
    a = 0.f;
    for (int k = 0; k < 256; ++k) a += o1S[k] * W1[k * 32 + tid];
    zS[tid] = fmaxf(a + b1[tid], 0.f);
  }
  __syncthreads();
  if (tid < 3) {
    a = 0.f;
    for (int j = 0; j < 32; ++j) a += zS[j] * W2[j * 3 + tid];
    out[b * 3 + tid] = a + b2[tid];
  }
}

// ---------------------------------------------------------------- launch
extern "C" void kernel_launch(void* const* d_in, const int* in_sizes, int n_in,
                              void* d_out, int out_size, void* d_ws, size_t ws_size,
                              hipStream_t stream) {
  const float* x  = (const float*)d_in[0];
  const float* Wi = (const float*)d_in[1];
  const float* Wh = (const float*)d_in[2];
  const float* bG = (const float*)d_in[3];
  const float* Wq = (const float*)d_in[4];
  const float* bq = (const float*)d_in[5];
  const float* Wk = (const float*)d_in[6];
  const float* bk = (const float*)d_in[7];
  const float* Wv = (const float*)d_in[8];
  const float* bv = (const float*)d_in[9];
  const float* Wo = (const float*)d_in[10];
  const float* bo = (const float*)d_in[11];
  const float* W1 = (const float*)d_in[12];
  const float* b1 = (const float*)d_in[13];
  const float* W2 = (const float*)d_in[14];
  const float* b2 = (const float*)d_in[15];
  float* out = (float*)d_out;
  char* ws = (char*)d_ws;

  unsigned short* xg    = (unsigned short*)(ws);              // 67,108,864 B
  unsigned short* hout  = (unsigned short*)(ws + 67108864);   // 16,777,216 B
  unsigned short* xbf   = (unsigned short*)(ws + 83886080);   // 16,777,216 B
  unsigned short* WiT   = (unsigned short*)(ws + 100663296);  //    524,288 B
  unsigned short* hx    = (unsigned short*)(ws + 101187584);  //     65,536 B
  unsigned*       flags = (unsigned*)(ws + 101253120);        //    131,072 B
  float*          us    = (float*)(ws + 101384192);           //     65,536 B
  float*          cbuf  = (float*)(ws + 101449728);           //      1,024 B
  float*          hbar  = (float*)(ws + 101450752);           //     65,536 B
  // total ~96.8 MB of workspace

  prep_x<<<dim3(8192), dim3(256), 0, stream>>>(x, xbf);
  prep_wit<<<dim3(256), dim3(256), 0, stream>>>(Wi, WiT);
  zero_flags<<<dim3(128), dim3(256), 0, stream>>>(flags);
  xg_gemm<<<dim3(8, 256), dim3(256), 0, stream>>>(xbf, WiT, bG, xg);
  lstm_scan<<<dim3(64), dim3(256), 0, stream>>>(Wh, xg, hout, hx, flags);
  attn_qu<<<dim3(64), dim3(256), 0, stream>>>(hout, Wq, bq, Wk, bk, us, cbuf);
  attn_sm<<<dim3(64), dim3(256), 0, stream>>>(hout, us, cbuf, hbar);
  head_k<<<dim3(64), dim3(256), 0, stream>>>(hbar, Wv, bv, Wo, bo, W1, b1, W2, b2, out);
}

// Round 2
// 1704.537 us; speedup vs baseline: 1.2873x; 1.2873x over previous
//
#include <hip/hip_runtime.h>
#include <hip/hip_bf16.h>

// ---------------------------------------------------------------------------
// myLSTM: LSTM(B=64,T=512,D=256,H=256) + single-head attn (only t=0 query is
// consumed by the head!) + MLP head.
// Pipeline:
//   prep_x      : x fp32 -> bf16 (same layout)
//   prep_wit    : Wi fp32 [256,1024] -> bf16 transposed [1024,256]
//   zero_flags  : clear inter-WG sync flags (ws is poisoned 0xAA every call)
//   xg_gemm     : xg = x@Wi + b   (bf16 MFMA, 128x128 tiles, bf16 output)
//   lstm_scan   : persistent 64-WG kernel, 512 steps, h exchanged via
//                 RELAXED agent-scope stores/loads + manual vmcnt waits
//                 (NO compiler release/acquire fences: those emit buffer_wbl2 /
//                  buffer_inv = full L2 writeback/invalidate per op — that was
//                  the 3.8us/step bottleneck in round 1)
//   attn_qu     : q0 = h0@Wq+bq ; u = Wk@(scale*q0) ; cb = scale*q0.bk
//   attn_sm     : scores = u.h[b,t]+cb -> softmax -> hbar = sum attn*h
//   head        : o0=hbar@Wv+bv ; o1=o0@Wo+bo ; z=relu(o1@W1+b1) ; out=z@W2+b2
// ---------------------------------------------------------------------------

typedef __attribute__((ext_vector_type(8))) short short8;   // 8 x bf16 (4 VGPR)
typedef __attribute__((ext_vector_type(4))) float float4v;  // MFMA acc

__device__ __forceinline__ unsigned short f2bf(float f) {  // RNE f32->bf16
  unsigned u = __builtin_bit_cast(unsigned, f);
  return (unsigned short)((u + 0x7fffu + ((u >> 16) & 1u)) >> 16);
}
__device__ __forceinline__ float bf2f(unsigned short h) {
  return __builtin_bit_cast(float, ((unsigned)h) << 16);
}
__device__ __forceinline__ float bcl(unsigned u) {  // low bf16 of dword
  return __builtin_bit_cast(float, u << 16);
}
__device__ __forceinline__ float bch(unsigned u) {  // high bf16 of dword
  return __builtin_bit_cast(float, u & 0xffff0000u);
}
__device__ __forceinline__ float sigm(float x) { return 1.f / (1.f + __expf(-x)); }
__device__ __forceinline__ float tanh_f(float x) { return 1.f - 2.f / (1.f + __expf(2.f * x)); }

// ---------------------------------------------------------------- prep kernels
__global__ void prep_x(const float* __restrict__ x, unsigned short* __restrict__ xbf) {
  size_t i = ((size_t)blockIdx.x * 256 + threadIdx.x) * 4;  // 8,388,608 elems
  float4 v = *(const float4*)&x[i];
  unsigned long long pk = (unsigned long long)f2bf(v.x)
                        | ((unsigned long long)f2bf(v.y) << 16)
                        | ((unsigned long long)f2bf(v.z) << 32)
                        | ((unsigned long long)f2bf(v.w) << 48);
  *(unsigned long long*)&xbf[i] = pk;
}

__global__ void prep_wit(const float* __restrict__ Wi, unsigned short* __restrict__ WiT) {
  size_t i = ((size_t)blockIdx.x * 256 + threadIdx.x) * 4;  // 262,144 elems
  float4 v = *(const float4*)&Wi[i];
  int k = (int)(i >> 10), n = (int)(i & 1023);
  WiT[(size_t)(n + 0) * 256 + k] = f2bf(v.x);
  WiT[(size_t)(n + 1) * 256 + k] = f2bf(v.y);
  WiT[(size_t)(n + 2) * 256 + k] = f2bf(v.z);
  WiT[(size_t)(n + 3) * 256 + k] = f2bf(v.w);
}

__global__ void zero_flags(unsigned* __restrict__ f) {
  f[(size_t)blockIdx.x * 256 + threadIdx.x] = 0u;  // 32768 dwords
}

// ---------------------------------------------------------------- xg = x@Wi+b
#define XKP 40  // LDS k-pitch (shorts): 80B rows -> 16B-aligned b128, ~2-way banks
__global__ __launch_bounds__(256) void xg_gemm(const unsigned short* __restrict__ xbf,
                                               const unsigned short* __restrict__ WiT,
                                               const float* __restrict__ bias,
                                               unsigned short* __restrict__ xg) {
  __shared__ unsigned short As[128 * XKP];
  __shared__ unsigned short Bs[128 * XKP];
  const int tid = threadIdx.x;
  const int n0 = blockIdx.x * 128, m0 = blockIdx.y * 128;
  const int wave = tid >> 6, lane = tid & 63, quad = lane >> 4, l16 = lane & 15;
  const int wm = wave >> 1, wn = wave & 1;

  float4v acc[4][4];
#pragma unroll
  for (int i = 0; i < 4; ++i)
#pragma unroll
    for (int j = 0; j < 4; ++j) acc[i][j] = (float4v){0.f, 0.f, 0.f, 0.f};

  const int rr = tid >> 2, c8 = (tid & 3) * 8;  // staging coords (16B per thread)
  for (int k0 = 0; k0 < 256; k0 += 32) {
#pragma unroll
    for (int pp = 0; pp < 2; ++pp) {
      int r = pp * 64 + rr;
      *(uint4*)&As[r * XKP + c8] = *(const uint4*)&xbf[(size_t)(m0 + r) * 256 + k0 + c8];
      *(uint4*)&Bs[r * XKP + c8] = *(const uint4*)&WiT[(size_t)(n0 + r) * 256 + k0 + c8];
    }
    __syncthreads();
#pragma unroll
    for (int mt = 0; mt < 4; ++mt) {
      short8 af = *(const short8*)&As[(wm * 64 + mt * 16 + l16) * XKP + quad * 8];
#pragma unroll
      for (int nt = 0; nt < 4; ++nt) {
        short8 bf = *(const short8*)&Bs[(wn * 64 + nt * 16 + l16) * XKP + quad * 8];
        acc[mt][nt] = __builtin_amdgcn_mfma_f32_16x16x32_bf16(af, bf, acc[mt][nt], 0, 0, 0);
      }
    }
    __syncthreads();
  }
  // epilogue: +bias, bf16 store.  C layout: col=lane&15, row=quad*4+reg.
#pragma unroll
  for (int nt = 0; nt < 4; ++nt) {
    int col = n0 + wn * 64 + nt * 16 + l16;
    float bv = bias[col];
#pragma unroll
    for (int mt = 0; mt < 4; ++mt) {
#pragma unroll
      for (int r = 0; r < 4; ++r) {
        int row = m0 + wm * 64 + mt * 16 + quad * 4 + r;
        xg[(size_t)row * 1024 + col] = f2bf(acc[mt][nt][r] + bv);
      }
    }
  }
}

// ---------------------------------------------------------------- LSTM scan
// 64 WGs: bg = wg>>4 (4 batch groups of 16), gg = wg&15 (16 units each).
// Wave w handles gate type w (cols w*16..w*16+15 of the local 64-col slice).
// Exchange protocol per step (all RELAXED agent-scope, no fences):
//   wave0: 64x 8B sc1 stores of h-slice -> s_waitcnt vmcnt(0) -> flag:=1
//   tid<16: spin on the 16 group flags (sc1 loads, no buffer_inv)
//   all: gather 8KB h_t with 8B sc1 loads -> LDS
#define KP2 264  // 528B rows: 16B aligned, 2-way banks on frag reads
__global__ __launch_bounds__(256) void lstm_scan(const float* __restrict__ Wh,
                                                 const unsigned short* __restrict__ xgbuf,
                                                 unsigned short* __restrict__ hout,
                                                 unsigned short* __restrict__ hx,
                                                 unsigned* __restrict__ flags) {
  __shared__ unsigned short WhS[64 * KP2];  // [local col][k] bf16
  __shared__ unsigned short hA[16 * KP2];   // [batch][k]  h_{t-1} bf16
  __shared__ float preS[16 * 68];           // [batch][local col] fp32
  __shared__ float cS[256];                 // [batch][unit] fp32 cell state
  __shared__ unsigned short hstage[256];    // [b_loc][u_loc] h_t bf16
  const int tid = threadIdx.x;
  const int wg = blockIdx.x, bg = wg >> 4, gg = wg & 15;
  const int wave = tid >> 6, lane = tid & 63, quad = lane >> 4, l16 = lane & 15;

  // stage Wh slice: WhS[gt*16+uu][k] = Wh[k][gt*256 + gg*16 + uu]   (bf16)
  {
    int uu = tid & 15, kh = tid >> 4;  // 16x16 threads
#pragma unroll
    for (int gt = 0; gt < 4; ++gt)
      for (int kb = 0; kb < 16; ++kb) {
        int k = kb * 16 + kh;
        WhS[(gt * 16 + uu) * KP2 + k] = f2bf(Wh[(size_t)k * 1024 + gt * 256 + gg * 16 + uu]);
      }
  }
  for (int i = tid; i < 16 * KP2; i += 256) hA[i] = 0;  // h_{-1} = 0
  cS[tid] = 0.f;                                        // c_{-1} = 0
  __syncthreads();

  const int b_loc = tid >> 4, u_loc = tid & 15;
  const size_t xg_base = ((size_t)(bg * 16 + b_loc) * 512) * 1024 + gg * 16 + u_loc;
  const size_t ho_base = ((size_t)(bg * 16 + b_loc) * 512) * 256 + gg * 16 + u_loc;
  const int nrow = wave * 16 + l16;

  for (int t = 0; t < 512; ++t) {
    // ---- prefetch xg_t early (plain loads; L2 stays warm — no cache invs)
    const unsigned short* xgp = xgbuf + xg_base + (size_t)t * 1024;
    unsigned short xi = xgp[0 * 256], xf = xgp[1 * 256];
    unsigned short xG = xgp[2 * 256], xo = xgp[3 * 256];

    // ---- MFMA: pre[b][c] = h_{t-1} @ WhSlice
    float4v acc = (float4v){0.f, 0.f, 0.f, 0.f};
#pragma unroll
    for (int kt = 0; kt < 8; ++kt) {
      short8 af = *(const short8*)&hA[l16 * KP2 + kt * 32 + quad * 8];
      short8 bf = *(const short8*)&WhS[nrow * KP2 + kt * 32 + quad * 8];
      acc = __builtin_amdgcn_mfma_f32_16x16x32_bf16(af, bf, acc, 0, 0, 0);
    }
#pragma unroll
    for (int r = 0; r < 4; ++r)
      preS[(quad * 4 + r) * 68 + wave * 16 + l16] = acc[r];
    __syncthreads();

    // ---- gates (fp32), h_t for own 16 units x 16 batches
    {
      float gi = preS[b_loc * 68 + 0 * 16 + u_loc] + bf2f(xi);
      float gf = preS[b_loc * 68 + 1 * 16 + u_loc] + bf2f(xf);
      float gG = preS[b_loc * 68 + 2 * 16 + u_loc] + bf2f(xG);
      float go = preS[b_loc * 68 + 3 * 16 + u_loc] + bf2f(xo);
      float c = sigm(gf) * cS[tid] + sigm(gi) * tanh_f(gG);
      cS[tid] = c;
      float h = sigm(go) * tanh_f(c);
      unsigned short hb = f2bf(h);
      hstage[b_loc * 16 + u_loc] = hb;           // LDS stage for wave0 push
      hout[ho_base + (size_t)t * 256] = hb;      // plain store (off-protocol)
    }
    __syncthreads();

    // ---- wave0 pushes the 512B slice as 64 x 8B agent-scope stores
    if (tid < 64) {
      int b2 = tid >> 2, q = tid & 3;
      const unsigned short* s = &hstage[b2 * 16 + q * 4];
      unsigned long long v = (unsigned long long)s[0]
                           | ((unsigned long long)s[1] << 16)
                           | ((unsigned long long)s[2] << 32)
                           | ((unsigned long long)s[3] << 48);
      int p = t & 1;
      unsigned long long* dst = (unsigned long long*)
          &hx[(((p * 4 + bg) * 16 + b2) * 256) + gg * 16 + q * 4];
      __hip_atomic_store(dst, v, __ATOMIC_RELAXED, __HIP_MEMORY_SCOPE_AGENT);
    }
    if (tid == 0) {
      asm volatile("s_waitcnt vmcnt(0)" ::: "memory");  // payload acked at IF
      __hip_atomic_store(&flags[(bg * 512 + t) * 16 + gg], 1u,
                         __ATOMIC_RELAXED, __HIP_MEMORY_SCOPE_AGENT);
    }

    // ---- wait for the 16 gate-group flags of this bg (cheap relaxed polls)
    if (tid < 16) {
      int guard = 0;
      while (__hip_atomic_load(&flags[(bg * 512 + t) * 16 + tid],
                               __ATOMIC_RELAXED, __HIP_MEMORY_SCOPE_AGENT) == 0 &&
             guard < (1 << 20))
        ++guard;
    }
    __syncthreads();

    // ---- gather full h_t [16][256] into hA (8B agent-scope loads)
    {
      int p = t & 1;
      int b2 = tid >> 4, u0 = (tid & 15) * 16;
      unsigned long long* src = (unsigned long long*)
          &hx[((p * 4 + bg) * 16 + b2) * 256 + u0];
#pragma unroll
      for (int i = 0; i < 4; ++i) {
        unsigned long long v = __hip_atomic_load(&src[i], __ATOMIC_RELAXED,
                                                 __HIP_MEMORY_SCOPE_AGENT);
        *(unsigned long long*)&hA[b2 * KP2 + u0 + i * 4] = v;
      }
    }
    __syncthreads();
  }
}

// ---------------------------------------------------------------- attention
__global__ __launch_bounds__(256) void attn_qu(const unsigned short* __restrict__ hout,
                                               const float* __restrict__ Wq,
                                               const float* __restrict__ bq,
                                               const float* __restrict__ Wk,
                                               const float* __restrict__ bk,
                                               float* __restrict__ us,
                                               float* __restrict__ cbuf) {
  __shared__ float h0S[256], q0S[256], red[256];
  const int b = blockIdx.x, tid = threadIdx.x;
  h0S[tid] = bf2f(hout[(size_t)b * 512 * 256 + tid]);
  __syncthreads();
  float a = 0.f;
  for (int k = 0; k < 256; ++k) a += h0S[k] * Wq[(size_t)k * 256 + tid];
  q0S[tid] = a + bq[tid];
  __syncthreads();
  red[tid] = q0S[tid] * bk[tid];
  __syncthreads();
  for (int s = 128; s > 0; s >>= 1) {
    if (tid < s) red[tid] += red[tid + s];
    __syncthreads();
  }
  if (tid == 0) cbuf[b] = 0.0625f * red[0];
  // u[d] = scale * dot(Wk row d, q0)
  float acc = 0.f;
  const float* wr = &Wk[(size_t)tid * 256];
  for (int e = 0; e < 256; e += 4) {
    float4 w = *(const float4*)&wr[e];
    acc += w.x * q0S[e] + w.y * q0S[e + 1] + w.z * q0S[e + 2] + w.w * q0S[e + 3];
  }
  us[b * 256 + tid] = 0.0625f * acc;
}

__global__ __launch_bounds__(256) void attn_sm(const unsigned short* __restrict__ hout,
                                               const float* __restrict__ us,
                                               const float* __restrict__ cbuf,
                                               float* __restrict__ hbar) {
  __shared__ float sS[512], red[256], hb4[4][256];
  const int b = blockIdx.x, tid = threadIdx.x, wave = tid >> 6, lane = tid & 63;
  const size_t hb_base = (size_t)b * 512 * 256;
  const float u0 = us[b * 256 + lane * 4 + 0], u1 = us[b * 256 + lane * 4 + 1];
  const float u2 = us[b * 256 + lane * 4 + 2], u3 = us[b * 256 + lane * 4 + 3];
  const float cbv = cbuf[b];
  for (int i = 0; i < 128; ++i) {
    int t = i * 4 + wave;
    unsigned long long hv = *(const unsigned long long*)&hout[hb_base + (size_t)t * 256 + lane * 4];
    unsigned lo = (unsigned)hv, hi = (unsigned)(hv >> 32);
    float p = u0 * bcl(lo) + u1 * bch(lo) + u2 * bcl(hi) + u3 * bch(hi);
    for (int m = 1; m < 64; m <<= 1) p += __shfl_xor(p, m, 64);
    if (lane == 0) sS[t] = p + cbv;
  }
  __syncthreads();
  red[tid] = fmaxf(sS[tid], sS[tid + 256]);
  __syncthreads();
  for (int s = 128; s > 0; s >>= 1) {
    if (tid < s) red[tid] = fmaxf(red[tid], red[tid + s]);
    __syncthreads();
  }
  float mx = red[0];
  __syncthreads();
  float e0 = __expf(sS[tid] - mx), e1 = __expf(sS[tid + 256] - mx);
  sS[tid] = e0; sS[tid + 256] = e1;
  red[tid] = e0 + e1;
  __syncthreads();
  for (int s = 128; s > 0; s >>= 1) {
    if (tid < s) red[tid] += red[tid + s];
    __syncthreads();
  }
  float inv = 1.f / red[0];
  // hbar[d] = (sum_t e[t]*h[t,d]) * inv  — per-wave partials over t
  float a0 = 0.f, a1 = 0.f, a2 = 0.f, a3 = 0.f;
  const int d0 = lane * 4;
  for (int i = 0; i < 128; ++i) {
    int t = wave * 128 + i;
    float w = sS[t];
    unsigned long long hv = *(const unsigned long long*)&hout[hb_base + (size_t)t * 256 + d0];
    unsigned lo = (unsigned)hv, hi = (unsigned)(hv >> 32);
    a0 += w * bcl(lo); a1 += w * bch(lo); a2 += w * bcl(hi); a3 += w * bch(hi);
  }
  hb4[wave][d0] = a0; hb4[wave][d0 + 1] = a1; hb4[wave][d0 + 2] = a2; hb4[wave][d0 + 3] = a3;
  __syncthreads();
  hbar[b * 256 + tid] = (hb4[0][tid] + hb4[1][tid] + hb4[2][tid] + hb4[3][tid]) * inv;
}

// ---------------------------------------------------------------- MLP head
__global__ __launch_bounds__(256) void head_k(const float* __restrict__ hbar,
                                              const float* __restrict__ Wv, const float* __restrict__ bv,
                                              const float* __restrict__ Wo, const float* __restrict__ bo,
                                              const float* __restrict__ W1, const float* __restrict__ b1,
                                              const float* __restrict__ W2, const float* __restrict__ b2,
                                              float* __restrict__ out) {
  __shared__ float hS[256], oS[256], o1S[256], zS[32];
  const int b = blockIdx.x, tid = threadIdx.x;
  hS[tid] = hbar[b * 256 + tid];
  __syncthreads();
  float a = 0.f;
  for (int k = 0; k < 256; ++k) a += hS[k] * Wv[(size_t)k * 256 + tid];
  oS[tid] = a + bv[tid];
  __syncthreads();
  a = 0.f;
  for (int k = 0; k < 256; ++k) a += oS[k] * Wo[(size_t)k * 256 + tid];
  o1S[tid] = a + bo[tid];
  __syncthreads();
  if (tid < 32) {
    a = 0.f;
    for (int k = 0; k < 256; ++k) a += o1S[k] * W1[k * 32 + tid];
    zS[tid] = fmaxf(a + b1[tid], 0.f);
  }
  __syncthreads();
  if (tid < 3) {
    a = 0.f;
    for (int j = 0; j < 32; ++j) a += zS[j] * W2[j * 3 + tid];
    out[b * 3 + tid] = a + b2[tid];
  }
}

// ---------------------------------------------------------------- launch
extern "C" void kernel_launch(void* const* d_in, const int* in_sizes, int n_in,
                              void* d_out, int out_size, void* d_ws, size_t ws_size,
                              hipStream_t stream) {
  const float* x  = (const float*)d_in[0];
  const float* Wi = (const float*)d_in[1];
  const float* Wh = (const float*)d_in[2];
  const float* bG = (const float*)d_in[3];
  const float* Wq = (const float*)d_in[4];
  const float* bq = (const float*)d_in[5];
  const float* Wk = (const float*)d_in[6];
  const float* bk = (const float*)d_in[7];
  const float* Wv = (const float*)d_in[8];
  const float* bv = (const float*)d_in[9];
  const float* Wo = (const float*)d_in[10];
  const float* bo = (const float*)d_in[11];
  const float* W1 = (const float*)d_in[12];
  const float* b1 = (const float*)d_in[13];
  const float* W2 = (const float*)d_in[14];
  const float* b2 = (const float*)d_in[15];
  float* out = (float*)d_out;
  char* ws = (char*)d_ws;

  unsigned short* xg    = (unsigned short*)(ws);              // 67,108,864 B
  unsigned short* hout  = (unsigned short*)(ws + 67108864);   // 16,777,216 B
  unsigned short* xbf   = (unsigned short*)(ws + 83886080);   // 16,777,216 B
  unsigned short* WiT   = (unsigned short*)(ws + 100663296);  //    524,288 B
  unsigned short* hx    = (unsigned short*)(ws + 101187584);  //     65,536 B
  unsigned*       flags = (unsigned*)(ws + 101253120);        //    131,072 B
  float*          us    = (float*)(ws + 101384192);           //     65,536 B
  float*          cbuf  = (float*)(ws + 101449728);           //      1,024 B
  float*          hbar  = (float*)(ws + 101450752);           //     65,536 B
  // total ~96.8 MB of workspace

  prep_x<<<dim3(8192), dim3(256), 0, stream>>>(x, xbf);
  prep_wit<<<dim3(256), dim3(256), 0, stream>>>(Wi, WiT);
  zero_flags<<<dim3(128), dim3(256), 0, stream>>>(flags);
  xg_gemm<<<dim3(8, 256), dim3(256), 0, stream>>>(xbf, WiT, bG, xg);
  lstm_scan<<<dim3(64), dim3(256), 0, stream>>>(Wh, xg, hout, hx, flags);
  attn_qu<<<dim3(64), dim3(256), 0, stream>>>(hout, Wq, bq, Wk, bk, us, cbuf);
  attn_sm<<<dim3(64), dim3(256), 0, stream>>>(hout, us, cbuf, hbar);
  head_k<<<dim3(64), dim3(256), 0, stream>>>(hbar, Wv, bv, Wo, bo, W1, b1, W2, b2, out);
}

// Round 4
// 1409.471 us; speedup vs baseline: 1.5568x; 1.2093x over previous
//
#include <hip/hip_runtime.h>
#include <hip/hip_bf16.h>

// ---------------------------------------------------------------------------
// myLSTM: LSTM(B=64,T=512,D=256,H=256) + single-head attn (only t=0 query is
// consumed by the head!) + MLP head.
// Pipeline:
//   prep_x      : x fp32 -> bf16 (same layout)
//   prep_wit    : Wi fp32 [256,1024] -> bf16 transposed [1024,256]
//   init_hx     : set all h-exchange tag dwords to 0xFFFFFFFF
//   xg_gemm     : xg = x@Wi + b   (bf16 MFMA, 128x128 tiles) written PERMUTED
//                 as [gg][b][t][gate*16+u] so the scan reads whole 128B lines
//   lstm_scan   : persistent 64-WG kernel, 512 steps. h exchanged via 8B
//                 TAGGED words {2 bf16 units | tag=t} using compiler-generated
//                 relaxed agent-scope atomics (global_store/load_dwordx2
//                 sc0 sc1). 8B store is single-copy-atomic => payload+tag
//                 visible together: ONE fabric leg per step — no release
//                 fence, no vmcnt ack, no separate flag, no separate gather.
//                 Double-buffered by t&1 (2-deep pipeline bound keeps it safe).
//   attn_qu     : q0 = h0@Wq+bq ; u = Wk@(scale*q0) ; cb = scale*q0.bk
//   attn_sm     : scores = u.h[b,t]+cb -> softmax -> hbar = sum attn*h
//   head        : o0=hbar@Wv+bv ; o1=o0@Wo+bo ; z=relu(o1@W1+b1) ; out=z@W2+b2
// ---------------------------------------------------------------------------

typedef __attribute__((ext_vector_type(8))) short short8;   // 8 x bf16 (4 VGPR)
typedef __attribute__((ext_vector_type(4))) float float4v;  // MFMA acc

__device__ __forceinline__ unsigned short f2bf(float f) {  // RNE f32->bf16
  unsigned u = __builtin_bit_cast(unsigned, f);
  return (unsigned short)((u + 0x7fffu + ((u >> 16) & 1u)) >> 16);
}
__device__ __forceinline__ float bf2f(unsigned short h) {
  return __builtin_bit_cast(float, ((unsigned)h) << 16);
}
__device__ __forceinline__ float bcl(unsigned u) {  // low bf16 of dword
  return __builtin_bit_cast(float, u << 16);
}
__device__ __forceinline__ float bch(unsigned u) {  // high bf16 of dword
  return __builtin_bit_cast(float, u & 0xffff0000u);
}
__device__ __forceinline__ float sigm(float x) { return 1.f / (1.f + __expf(-x)); }
__device__ __forceinline__ float tanh_f(float x) { return 1.f - 2.f / (1.f + __expf(2.f * x)); }

// ---------------------------------------------------------------- prep kernels
__global__ void prep_x(const float* __restrict__ x, unsigned short* __restrict__ xbf) {
  size_t i = ((size_t)blockIdx.x * 256 + threadIdx.x) * 4;  // 8,388,608 elems
  float4 v = *(const float4*)&x[i];
  unsigned long long pk = (unsigned long long)f2bf(v.x)
                        | ((unsigned long long)f2bf(v.y) << 16)
                        | ((unsigned long long)f2bf(v.z) << 32)
                        | ((unsigned long long)f2bf(v.w) << 48);
  *(unsigned long long*)&xbf[i] = pk;
}

__global__ void prep_wit(const float* __restrict__ Wi, unsigned short* __restrict__ WiT) {
  size_t i = ((size_t)blockIdx.x * 256 + threadIdx.x) * 4;  // 262,144 elems
  float4 v = *(const float4*)&Wi[i];
  int k = (int)(i >> 10), n = (int)(i & 1023);
  WiT[(size_t)(n + 0) * 256 + k] = f2bf(v.x);
  WiT[(size_t)(n + 1) * 256 + k] = f2bf(v.y);
  WiT[(size_t)(n + 2) * 256 + k] = f2bf(v.z);
  WiT[(size_t)(n + 3) * 256 + k] = f2bf(v.w);
}

__global__ void init_hx(unsigned long long* __restrict__ hx) {
  // tag dword := 0xFFFFFFFF (never equals any t in [0,512))
  hx[(size_t)blockIdx.x * 256 + threadIdx.x] = 0xffffffff00000000ULL;
}

// ---------------------------------------------------------------- xg = x@Wi+b
#define XKP 40  // LDS k-pitch (shorts): 80B rows -> 16B-aligned b128, ~2-way banks
__global__ __launch_bounds__(256) void xg_gemm(const unsigned short* __restrict__ xbf,
                                               const unsigned short* __restrict__ WiT,
                                               const float* __restrict__ bias,
                                               unsigned short* __restrict__ xg) {
  __shared__ unsigned short As[128 * XKP];
  __shared__ unsigned short Bs[128 * XKP];
  const int tid = threadIdx.x;
  const int n0 = blockIdx.x * 128, m0 = blockIdx.y * 128;
  const int wave = tid >> 6, lane = tid & 63, quad = lane >> 4, l16 = lane & 15;
  const int wm = wave >> 1, wn = wave & 1;

  float4v acc[4][4];
#pragma unroll
  for (int i = 0; i < 4; ++i)
#pragma unroll
    for (int j = 0; j < 4; ++j) acc[i][j] = (float4v){0.f, 0.f, 0.f, 0.f};

  const int rr = tid >> 2, c8 = (tid & 3) * 8;  // staging coords (16B per thread)
  for (int k0 = 0; k0 < 256; k0 += 32) {
#pragma unroll
    for (int pp = 0; pp < 2; ++pp) {
      int r = pp * 64 + rr;
      *(uint4*)&As[r * XKP + c8] = *(const uint4*)&xbf[(size_t)(m0 + r) * 256 + k0 + c8];
      *(uint4*)&Bs[r * XKP + c8] = *(const uint4*)&WiT[(size_t)(n0 + r) * 256 + k0 + c8];
    }
    __syncthreads();
#pragma unroll
    for (int mt = 0; mt < 4; ++mt) {
      short8 af = *(const short8*)&As[(wm * 64 + mt * 16 + l16) * XKP + quad * 8];
#pragma unroll
      for (int nt = 0; nt < 4; ++nt) {
        short8 bf = *(const short8*)&Bs[(wn * 64 + nt * 16 + l16) * XKP + quad * 8];
        acc[mt][nt] = __builtin_amdgcn_mfma_f32_16x16x32_bf16(af, bf, acc[mt][nt], 0, 0, 0);
      }
    }
    __syncthreads();
  }
  // epilogue: +bias, bf16 store, PERMUTED layout for the scan:
  //   xg[((gg*64 + b)*512 + t)*64 + gate*16 + u]
  // C layout: col=lane&15, row=quad*4+reg.
#pragma unroll
  for (int nt = 0; nt < 4; ++nt) {
    int col = n0 + wn * 64 + nt * 16 + l16;
    int gate = col >> 8, ggx = (col >> 4) & 15, ul = col & 15;
    float bv = bias[col];
#pragma unroll
    for (int mt = 0; mt < 4; ++mt) {
#pragma unroll
      for (int r = 0; r < 4; ++r) {
        int row = m0 + wm * 64 + mt * 16 + quad * 4 + r;
        int b = row >> 9, t = row & 511;
        xg[(((size_t)ggx * 64 + b) * 512 + t) * 64 + gate * 16 + ul] =
            f2bf(acc[mt][nt][r] + bv);
      }
    }
  }
}

// ---------------------------------------------------------------- LSTM scan
// 64 WGs: bg = wg>>4 (4 batch groups of 16), gg = wg&15 (16 units each).
// Wave w computes gate type w's 16 columns via MFMA.
// hx word layout (ull): [parity][batch(64)][word(128)] where word w holds
// units 2w,2w+1 as {lo: u0|u1<<16, hi: tag}, tag = t.
#define KP2 264  // 528B rows: 16B aligned, 2-way banks on frag reads
__global__ __launch_bounds__(256) void lstm_scan(const float* __restrict__ Wh,
                                                 const unsigned short* __restrict__ xgbuf,
                                                 unsigned short* __restrict__ hout,
                                                 unsigned long long* __restrict__ hx) {
  __shared__ unsigned short WhS[64 * KP2];  // [local col][k] bf16
  __shared__ unsigned short hA[16 * KP2];   // [batch][k]  h_{t-1} bf16
  __shared__ float preS[16 * 68];           // [batch][local col] fp32
  __shared__ float cS[256];                 // [batch][unit] fp32 cell state
  const int tid = threadIdx.x;
  const int wg = blockIdx.x, bg = wg >> 4, gg = wg & 15;
  const int wave = tid >> 6, lane = tid & 63, quad = lane >> 4, l16 = lane & 15;

  // stage Wh slice: WhS[gt*16+uu][k] = Wh[k][gt*256 + gg*16 + uu]   (bf16)
  {
    int uu = tid & 15, kh = tid >> 4;  // 16x16 threads
#pragma unroll
    for (int gt = 0; gt < 4; ++gt)
      for (int kb = 0; kb < 16; ++kb) {
        int k = kb * 16 + kh;
        WhS[(gt * 16 + uu) * KP2 + k] = f2bf(Wh[(size_t)k * 1024 + gt * 256 + gg * 16 + uu]);
      }
  }
  for (int i = tid; i < 16 * KP2; i += 256) hA[i] = 0;  // h_{-1} = 0
  cS[tid] = 0.f;                                        // c_{-1} = 0
  __syncthreads();

  const int b_loc = tid >> 4, u_loc = tid & 15;
  const int bgb = bg * 16 + b_loc;            // global batch of this thread
  const int u_glob = gg * 16 + u_loc;         // global unit of this thread
  const int nrow = wave * 16 + l16;
  const unsigned short* xgp0 = xgbuf + ((size_t)(gg * 64 + bgb) * 512) * 64 + u_loc;

  // preload xg(0)
  unsigned short xi = xgp0[0], xf = xgp0[16], xG = xgp0[32], xo = xgp0[48];

  for (int t = 0; t < 512; ++t) {
    // ---- MFMA: pre[b][c] = h_{t-1} @ WhSlice
    float4v acc = (float4v){0.f, 0.f, 0.f, 0.f};
#pragma unroll
    for (int kt = 0; kt < 8; ++kt) {
      short8 af = *(const short8*)&hA[l16 * KP2 + kt * 32 + quad * 8];
      short8 bf = *(const short8*)&WhS[nrow * KP2 + kt * 32 + quad * 8];
      acc = __builtin_amdgcn_mfma_f32_16x16x32_bf16(af, bf, acc, 0, 0, 0);
    }
#pragma unroll
    for (int r = 0; r < 4; ++r)
      preS[(quad * 4 + r) * 68 + wave * 16 + l16] = acc[r];

    // ---- prefetch xg(t+1) (consumed NEXT iteration; full step to cover)
    int tn = (t < 511) ? t + 1 : t;
    const unsigned short* xgn = xgp0 + (size_t)tn * 64;
    unsigned short nxi = xgn[0], nxf = xgn[16], nxG = xgn[32], nxo = xgn[48];
    __syncthreads();

    // ---- gates (fp32): this thread owns (batch=bgb, unit=u_glob)
    float gi = preS[b_loc * 68 + 0 * 16 + u_loc] + bf2f(xi);
    float gf = preS[b_loc * 68 + 1 * 16 + u_loc] + bf2f(xf);
    float gG = preS[b_loc * 68 + 2 * 16 + u_loc] + bf2f(xG);
    float go = preS[b_loc * 68 + 3 * 16 + u_loc] + bf2f(xo);
    float c = sigm(gf) * cS[tid] + sigm(gi) * tanh_f(gG);
    cS[tid] = c;
    float h = sigm(go) * tanh_f(c);
    unsigned hb = (unsigned)f2bf(h);
    hA[b_loc * KP2 + u_glob] = (unsigned short)hb;  // own slice direct to LDS

    // ---- pack 2 units/word via shfl; even-u threads store tagged 8B word
    const unsigned tg = (unsigned)t;
    unsigned v1 = __shfl_down((int)hb, 1);
    if ((u_loc & 1) == 0) {
      unsigned d0 = hb | (v1 << 16);
      unsigned long long val = (unsigned long long)d0 | ((unsigned long long)tg << 32);
      unsigned long long* dst =
          hx + (((size_t)(t & 1) * 64 + bgb) * 128 + (u_glob >> 1));
      __hip_atomic_store(dst, val, __ATOMIC_RELAXED, __HIP_MEMORY_SCOPE_AGENT);
      // h history for attention (plain cached store)
      *(unsigned*)&hout[((size_t)bgb * 512 + t) * 256 + u_glob] = d0;
    }

    // ---- consume: thread (b2 = tid>>4, group grp = tid&15) polls 8 words
    {
      int b2 = tid >> 4, grp = tid & 15;
      if (grp != gg) {  // own group already written to LDS above
        const unsigned long long* base =
            hx + (((size_t)(t & 1) * 64 + bg * 16 + b2) * 128 + grp * 8);
        unsigned long long w[8];
        int guard = 0;
        bool ok;
        do {
          ok = true;
#pragma unroll
          for (int i = 0; i < 8; ++i) {
            w[i] = __hip_atomic_load(&base[i], __ATOMIC_RELAXED,
                                     __HIP_MEMORY_SCOPE_AGENT);
            ok &= ((unsigned)(w[i] >> 32) == tg);
          }
        } while (!ok && ++guard < (1 << 20));
        int u0 = grp * 16;
#pragma unroll
        for (int i = 0; i < 8; ++i)
          *(unsigned*)&hA[b2 * KP2 + u0 + 2 * i] = (unsigned)w[i];
      }
    }
    xi = nxi; xf = nxf; xG = nxG; xo = nxo;
    __syncthreads();
  }
}

// ---------------------------------------------------------------- attention
__global__ __launch_bounds__(256) void attn_qu(const unsigned short* __restrict__ hout,
                                               const float* __restrict__ Wq,
                                               const float* __restrict__ bq,
                                               const float* __restrict__ Wk,
                                               const float* __restrict__ bk,
                                               float* __restrict__ us,
                                               float* __restrict__ cbuf) {
  __shared__ float h0S[256], q0S[256], red[256];
  const int b = blockIdx.x, tid = threadIdx.x;
  h0S[tid] = bf2f(hout[(size_t)b * 512 * 256 + tid]);
  __syncthreads();
  float a = 0.f;
  for (int k = 0; k < 256; ++k) a += h0S[k] * Wq[(size_t)k * 256 + tid];
  q0S[tid] = a + bq[tid];
  __syncthreads();
  red[tid] = q0S[tid] * bk[tid];
  __syncthreads();
  for (int s = 128; s > 0; s >>= 1) {
    if (tid < s) red[tid] += red[tid + s];
    __syncthreads();
  }
  if (tid == 0) cbuf[b] = 0.0625f * red[0];
  // u[d] = scale * dot(Wk row d, q0)
  float acc = 0.f;
  const float* wr = &Wk[(size_t)tid * 256];
  for (int e = 0; e < 256; e += 4) {
    float4 w = *(const float4*)&wr[e];
    acc += w.x * q0S[e] + w.y * q0S[e + 1] + w.z * q0S[e + 2] + w.w * q0S[e + 3];
  }
  us[b * 256 + tid] = 0.0625f * acc;
}

__global__ __launch_bounds__(256) void attn_sm(const unsigned short* __restrict__ hout,
                                               const float* __restrict__ us,
                                               const float* __restrict__ cbuf,
                                               float* __restrict__ hbar) {
  __shared__ float sS[512], red[256], hb4[4][256];
  const int b = blockIdx.x, tid = threadIdx.x, wave = tid >> 6, lane = tid & 63;
  const size_t hb_base = (size_t)b * 512 * 256;
  const float u0 = us[b * 256 + lane * 4 + 0], u1 = us[b * 256 + lane * 4 + 1];
  const float u2 = us[b * 256 + lane * 4 + 2], u3 = us[b * 256 + lane * 4 + 3];
  const float cbv = cbuf[b];
  for (int i = 0; i < 128; ++i) {
    int t = i * 4 + wave;
    unsigned long long hv = *(const unsigned long long*)&hout[hb_base + (size_t)t * 256 + lane * 4];
    unsigned lo = (unsigned)hv, hi = (unsigned)(hv >> 32);
    float p = u0 * bcl(lo) + u1 * bch(lo) + u2 * bcl(hi) + u3 * bch(hi);
    for (int m = 1; m < 64; m <<= 1) p += __shfl_xor(p, m, 64);
    if (lane == 0) sS[t] = p + cbv;
  }
  __syncthreads();
  red[tid] = fmaxf(sS[tid], sS[tid + 256]);
  __syncthreads();
  for (int s = 128; s > 0; s >>= 1) {
    if (tid < s) red[tid] = fmaxf(red[tid], red[tid + s]);
    __syncthreads();
  }
  float mx = red[0];
  __syncthreads();
  float e0 = __expf(sS[tid] - mx), e1 = __expf(sS[tid + 256] - mx);
  sS[tid] = e0; sS[tid + 256] = e1;
  red[tid] = e0 + e1;
  __syncthreads();
  for (int s = 128; s > 0; s >>= 1) {
    if (tid < s) red[tid] += red[tid + s];
    __syncthreads();
  }
  float inv = 1.f / red[0];
  // hbar[d] = (sum_t e[t]*h[t,d]) * inv  — per-wave partials over t
  float a0 = 0.f, a1 = 0.f, a2 = 0.f, a3 = 0.f;
  const int d0 = lane * 4;
  for (int i = 0; i < 128; ++i) {
    int t = wave * 128 + i;
    float w = sS[t];
    unsigned long long hv = *(const unsigned long long*)&hout[hb_base + (size_t)t * 256 + d0];
    unsigned lo = (unsigned)hv, hi = (unsigned)(hv >> 32);
    a0 += w * bcl(lo); a1 += w * bch(lo); a2 += w * bcl(hi); a3 += w * bch(hi);
  }
  hb4[wave][d0] = a0; hb4[wave][d0 + 1] = a1; hb4[wave][d0 + 2] = a2; hb4[wave][d0 + 3] = a3;
  __syncthreads();
  hbar[b * 256 + tid] = (hb4[0][tid] + hb4[1][tid] + hb4[2][tid] + hb4[3][tid]) * inv;
}

// ---------------------------------------------------------------- MLP head
__global__ __launch_bounds__(256) void head_k(const float* __restrict__ hbar,
                                              const float* __restrict__ Wv, const float* __restrict__ bv,
                                              const float* __restrict__ Wo, const float* __restrict__ bo,
                                              const float* __restrict__ W1, const float* __restrict__ b1,
                                              const float* __restrict__ W2, const float* __restrict__ b2,
                                              float* __restrict__ out) {
  __shared__ float hS[256], oS[256], o1S[256], zS[32];
  const int b = blockIdx.x, tid = threadIdx.x;
  hS[tid] = hbar[b * 256 + tid];
  __syncthreads();
  float a = 0.f;
  for (int k = 0; k < 256; ++k) a += hS[k] * Wv[(size_t)k * 256 + tid];
  oS[tid] = a + bv[tid];
  __syncthreads();
  a = 0.f;
  for (int k = 0; k < 256; ++k) a += oS[k] * Wo[(size_t)k * 256 + tid];
  o1S[tid] = a + bo[tid];
  __syncthreads();
  if (tid < 32) {
    a = 0.f;
    for (int k = 0; k < 256; ++k) a += o1S[k] * W1[k * 32 + tid];
    zS[tid] = fmaxf(a + b1[tid], 0.f);
  }
  __syncthreads();
  if (tid < 3) {
    a = 0.f;
    for (int j = 0; j < 32; ++j) a += zS[j] * W2[j * 3 + tid];
    out[b * 3 + tid] = a + b2[tid];
  }
}

// ---------------------------------------------------------------- launch
extern "C" void kernel_launch(void* const* d_in, const int* in_sizes, int n_in,
                              void* d_out, int out_size, void* d_ws, size_t ws_size,
                              hipStream_t stream) {
  const float* x  = (const float*)d_in[0];
  const float* Wi = (const float*)d_in[1];
  const float* Wh = (const float*)d_in[2];
  const float* bG = (const float*)d_in[3];
  const float* Wq = (const float*)d_in[4];
  const float* bq = (const float*)d_in[5];
  const float* Wk = (const float*)d_in[6];
  const float* bk = (const float*)d_in[7];
  const float* Wv = (const float*)d_in[8];
  const float* bv = (const float*)d_in[9];
  const float* Wo = (const float*)d_in[10];
  const float* bo = (const float*)d_in[11];
  const float* W1 = (const float*)d_in[12];
  const float* b1 = (const float*)d_in[13];
  const float* W2 = (const float*)d_in[14];
  const float* b2 = (const float*)d_in[15];
  float* out = (float*)d_out;
  char* ws = (char*)d_ws;

  unsigned short* xg    = (unsigned short*)(ws);              // 67,108,864 B
  unsigned short* hout  = (unsigned short*)(ws + 67108864);   // 16,777,216 B
  unsigned short* xbf   = (unsigned short*)(ws + 83886080);   // 16,777,216 B
  unsigned short* WiT   = (unsigned short*)(ws + 100663296);  //    524,288 B
  unsigned long long* hx = (unsigned long long*)(ws + 101187584);  // 131,072 B
  float*          us    = (float*)(ws + 101318656);           //     65,536 B
  float*          cbuf  = (float*)(ws + 101384192);           //      1,024 B
  float*          hbar  = (float*)(ws + 101385216);           //     65,536 B
  // total ~101.5 MB of workspace

  prep_x<<<dim3(8192), dim3(256), 0, stream>>>(x, xbf);
  prep_wit<<<dim3(256), dim3(256), 0, stream>>>(Wi, WiT);
  init_hx<<<dim3(64), dim3(256), 0, stream>>>(hx);
  xg_gemm<<<dim3(8, 256), dim3(256), 0, stream>>>(xbf, WiT, bG, xg);
  lstm_scan<<<dim3(64), dim3(256), 0, stream>>>(Wh, xg, hout, hx);
  attn_qu<<<dim3(64), dim3(256), 0, stream>>>(hout, Wq, bq, Wk, bk, us, cbuf);
  attn_sm<<<dim3(64), dim3(256), 0, stream>>>(hout, us, cbuf, hbar);
  head_k<<<dim3(64), dim3(256), 0, stream>>>(hbar, Wv, bv, Wo, bo, W1, b1, W2, b2, out);
}